// Round 10
// baseline (181.627 us; speedup 1.0000x reference)
//
#include <hip/hip_runtime.h>
#include <math.h>

#define NB 32
#define NN 262144
#define NG 256
#define NC 128            // chunks per batch
#define CH (NN/NC)        // 2048 elements per chunk
#define SC (CH/4)         // 512 elements per wave (4 waves/block)
#define CD 64             // chunks per batch, apply pass
#define ELD (NN/CD)       // 4096 elements per apply block

// ---- Pass 1: per-(batch,chunk,WAVE,group) counts (packed u16x4) + compact
//      u16 chunk totals + packed u8 gid emission. Wave w counts exactly
//      elements [w*512,(w+1)*512) so the counts seed k_scatter's running
//      counters directly. 4 KB LDS -> 8 blocks/CU. ----
__global__ __launch_bounds__(256, 8) void k_count(const int* __restrict__ vr,
                                                  unsigned long long* __restrict__ wcnt16,
                                                  unsigned short* __restrict__ cnt16,
                                                  unsigned* __restrict__ gid32){
  __shared__ unsigned sc[4][NG];
  const int t    = threadIdx.x;
  const int lane = t & 63;
  const int w    = t >> 6;
  sc[0][t] = 0u; sc[1][t] = 0u; sc[2][t] = 0u; sc[3][t] = 0u;
  __syncthreads();

  const int b = blockIdx.x / NC;
  const int c = blockIdx.x % NC;
  const size_t base = (size_t)b*NN + (size_t)c*CH;
  const int4* v4 = (const int4*)(vr + base);

#pragma unroll
  for (int i = 0; i < 2; i++){
    int idx = w*128 + i*64 + lane;        // int4 idx; wave w owns [w*512,(w+1)*512)
    int4 v = v4[idx];
    atomicAdd(&sc[w][v.x], 1u);
    atomicAdd(&sc[w][v.y], 1u);
    atomicAdd(&sc[w][v.z], 1u);
    atomicAdd(&sc[w][v.w], 1u);
    gid32[(base >> 2) + idx] =
      (unsigned)v.x | ((unsigned)v.y << 8) | ((unsigned)v.z << 16) | ((unsigned)v.w << 24);
  }
  __syncthreads();

  unsigned c0 = sc[0][t], c1 = sc[1][t], c2 = sc[2][t], c3 = sc[3][t];
  const size_t cb = (size_t)b*NC + c;
  wcnt16[cb*NG + t] = (unsigned long long)c0
                    | ((unsigned long long)c1 << 16)
                    | ((unsigned long long)c2 << 32)
                    | ((unsigned long long)c3 << 48);
  cnt16[cb*NG + t] = (unsigned short)(c0 + c1 + c2 + c3);
}

// ---- Pass 2: LDS-staged stable sort of each chunk + coalesced flush ----
// CH=2048: 15.2 KB LDS -> 8 blocks/CU (32 waves, 100% theoretical occupancy);
// 4096-block grid = exactly 2 resident rounds. Offsets self-computed from the
// L2-hot compact cnt16 column (u16 -> same L2 traffic as R9's u64/64-chunk
// walk). Placement = ds_add_rtn on seeded per-wave counters (R9-proven
// lane-ordered). Element order bit-exact: chunk size doesn't change run
// concatenation order (chunk-major) nor within-chunk wave/stripe/lane order.
__global__ __launch_bounds__(256, 8) void k_scatter(const float* __restrict__ pr,
                                                    const unsigned* __restrict__ gid32,
                                                    const unsigned long long* __restrict__ wcnt16,
                                                    const unsigned short* __restrict__ cnt16,
                                                    float* __restrict__ sorted,
                                                    unsigned* __restrict__ grpbase,
                                                    unsigned* __restrict__ grplen){
  __shared__ float vbuf[CH];            // 8 KB sorted values
  __shared__ unsigned char gbuf[CH];    // 2 KB gid per sorted slot
  __shared__ unsigned wcnt[4][NG];      // 4 KB running counters (seeded)
  __shared__ unsigned bias[NG];         // 1 KB global_dest - local_base
  __shared__ unsigned wsumA[4];
  __shared__ unsigned wsumO[4];
  const int t    = threadIdx.x;
  const int lane = t & 63;
  const int w    = t >> 6;
  const int b = blockIdx.x / NC;
  const int c = blockIdx.x % NC;
  const size_t base = (size_t)b*NN + (size_t)c*CH;

  // phase 0: walk compact totals column; fused shfl scans; seed counters
  {
    const unsigned short* colT = cnt16 + (size_t)b*NC*NG + t;
    unsigned tot_all = 0, tot_before = 0;
#pragma unroll 8
    for (int cc = 0; cc < NC; cc++){
      unsigned tt = colT[(size_t)cc*NG];
      tot_all += tt;
      if (cc < c) tot_before += tt;     // uniform branch per block
    }
    unsigned long long own = wcnt16[((size_t)b*NC + c)*NG + t];
    unsigned lo = (unsigned)own, hi = (unsigned)(own >> 32);
    unsigned w0 = lo & 0xFFFFu, w1 = lo >> 16, w2 = hi & 0xFFFFu, w3 = hi >> 16;
    unsigned tot_own = w0 + w1 + w2 + w3;

    unsigned va = tot_all, vo = tot_own;        // wave-inclusive scans
#pragma unroll
    for (int d = 1; d < 64; d <<= 1){
      unsigned ya = __shfl_up(va, d, 64);
      unsigned yo = __shfl_up(vo, d, 64);
      if (lane >= d){ va += ya; vo += yo; }
    }
    if (lane == 63){ wsumA[w] = va; wsumO[w] = vo; }
    __syncthreads();
    unsigned preA = 0, preO = 0;
#pragma unroll
    for (int k = 0; k < 3; k++) if (k < w){ preA += wsumA[k]; preO += wsumO[k]; }
    unsigned base_g = preA + va - tot_all;      // group base (global)
    unsigned lb     = preO + vo - tot_own;      // local exclusive prefix
    wcnt[0][t] = lb;
    wcnt[1][t] = lb + w0;
    wcnt[2][t] = lb + w0 + w1;
    wcnt[3][t] = lb + w0 + w1 + w2;
    bias[t] = (base_g + tot_before) - lb;
    if (c == 0){                                // publish for k_sum
      grpbase[b*NG + t] = base_g;
      grplen [b*NG + t] = tot_all;
    }
  }
  __syncthreads();

  // phase 1: stable scatter into LDS via ds_add_rtn placement (per wave,
  // element order; stripes in program order, pipelined independent atomics)
  {
    const float*    psrc = pr    + base        + (size_t)w*SC;
    const unsigned* gsrc = gid32 + (base >> 2) + (size_t)w*(SC/4);
    const int shft = (lane & 3) * 8;

    float pv[8]; unsigned pk[8];                // batch all loads upfront
#pragma unroll
    for (int s = 0; s < 8; s++){
      pv[s] = psrc[s*64 + lane];
      pk[s] = gsrc[s*16 + (lane >> 2)];         // 4 lanes share one word
    }
#pragma unroll
    for (int s = 0; s < 8; s++){
      int g = (int)((pk[s] >> shft) & 255u);
      unsigned slot = atomicAdd(&wcnt[w][g], 1u);   // ds_add_rtn_u32
      vbuf[slot] = pv[s];
      gbuf[slot] = (unsigned char)g;
    }
  }
  __syncthreads();

  // phase 2: coalesced flush (consecutive p -> consecutive dest within runs)
  {
    float* dst = sorted + (size_t)b*NN;
    const unsigned* gbuf32 = (const unsigned*)gbuf;
#pragma unroll
    for (int k = 0; k < CH/256; k++){      // 8 iters
      int p = k*256 + t;
      unsigned packed = gbuf32[p >> 2];    // broadcast within 4 threads
      unsigned g = (packed >> ((p & 3) * 8)) & 255u;
      dst[bias[g] + (unsigned)p] = vbuf[p];
    }
  }
}

// ---- Pass 3: one LANE per (batch,group); float4 loads, 8-deep register
//      pipeline. Scalar head to 16B alignment + scalar tail keep the fp32 add
//      chain in exact element order (bit-exact). ----
__global__ __launch_bounds__(32) void k_sum(const float* __restrict__ sorted,
                                            const unsigned* __restrict__ grpbase,
                                            const unsigned* __restrict__ grplen,
                                            float* __restrict__ gsum,
                                            float* __restrict__ gmn,
                                            float* __restrict__ gmx){
  const int lane = threadIdx.x;                  // 0..31
  const int b = blockIdx.x >> 3;                 // 8 blocks per batch
  const int g = ((blockIdx.x & 7) << 5) + lane;  // one group per lane

  const unsigned base = grpbase[b*NG + g];
  const unsigned len  = grplen [b*NG + g];
  const float* sp = sorted + (size_t)b*NN + base;

  float s = 0.0f, mn = INFINITY, mx = -INFINITY;

  unsigned head = (4u - ((unsigned)(((size_t)sp) >> 2) & 3u)) & 3u;
  if (head > len) head = len;
  for (unsigned i = 0; i < head; i++){
    float v = sp[i];
    s = __fadd_rn(s, v); mn = fminf(mn, v); mx = fmaxf(mx, v);
  }
  const float4* f4 = (const float4*)(sp + head);
  const unsigned rem   = len - head;
  const unsigned nfull = rem >> 4;               // 16-elem batches (4 x float4)

  float4 b0[4], b1[4], b2[4], b3[4], b4[4], b5[4], b6[4], b7[4];
#define LOADV(D, K) { D[0]=f4[(K)*4+0]; D[1]=f4[(K)*4+1]; D[2]=f4[(K)*4+2]; D[3]=f4[(K)*4+3]; }
#define CONS1(V)    { s=__fadd_rn(s,(V)); mn=fminf(mn,(V)); mx=fmaxf(mx,(V)); }
#define CONSV(D)    { _Pragma("unroll") for (int j = 0; j < 4; j++){ float4 q = D[j]; \
                      CONS1(q.x) CONS1(q.y) CONS1(q.z) CONS1(q.w) } }

  if (nfull > 0) LOADV(b0, 0)
  if (nfull > 1) LOADV(b1, 1)
  if (nfull > 2) LOADV(b2, 2)
  if (nfull > 3) LOADV(b3, 3)
  if (nfull > 4) LOADV(b4, 4)
  if (nfull > 5) LOADV(b5, 5)
  if (nfull > 6) LOADV(b6, 6)
  if (nfull > 7) LOADV(b7, 7)
  unsigned k = 0;
  for (; k + 8 <= nfull; k += 8){
    CONSV(b0) if (k +  8 < nfull) LOADV(b0, k +  8)
    CONSV(b1) if (k +  9 < nfull) LOADV(b1, k +  9)
    CONSV(b2) if (k + 10 < nfull) LOADV(b2, k + 10)
    CONSV(b3) if (k + 11 < nfull) LOADV(b3, k + 11)
    CONSV(b4) if (k + 12 < nfull) LOADV(b4, k + 12)
    CONSV(b5) if (k + 13 < nfull) LOADV(b5, k + 13)
    CONSV(b6) if (k + 14 < nfull) LOADV(b6, k + 14)
    CONSV(b7) if (k + 15 < nfull) LOADV(b7, k + 15)
  }
  {
    unsigned r = nfull - k;        // 0..7 remaining full batches in b0..b6
    if (r > 0) CONSV(b0)
    if (r > 1) CONSV(b1)
    if (r > 2) CONSV(b2)
    if (r > 3) CONSV(b3)
    if (r > 4) CONSV(b4)
    if (r > 5) CONSV(b5)
    if (r > 6) CONSV(b6)
  }
  for (unsigned i = head + (nfull << 4); i < len; i++){
    float v = sp[i];
    s = __fadd_rn(s, v); mn = fminf(mn, v); mx = fmaxf(mx, v);
  }
#undef LOADV
#undef CONS1
#undef CONSV

  gsum[b*NG + g] = s;
  gmn [b*NG + g] = mn;
  gmx [b*NG + g] = mx;
}

// ---- Pass 4: per-batch group pipeline (blend, stable rank, f0/f1, no_scale) ----
__global__ __launch_bounds__(256) void k_pipeline(const float* __restrict__ gsum,
                                                  const float* __restrict__ gmn,
                                                  const float* __restrict__ gmx,
                                                  const float* __restrict__ inp_means,
                                                  const float* __restrict__ Wv,
                                                  float* __restrict__ params){
  const int b = blockIdx.x;
  const int g = threadIdx.x;
  __shared__ float vm[NG];
  __shared__ float vs[NG];

  const float s   = gsum[b*NG + g];
  const float mnf = gmn [b*NG + g];
  const float mxf = gmx [b*NG + g];
  const float W0 = Wv[0], W1 = Wv[1];
  float mean = __fdiv_rn(__fadd_rn(__fmul_rn(inp_means[b*NG + g], W0),
                                   __fmul_rn(s, W1)),
                         __fadd_rn(W0, W1));
  vm[g] = mean;
  __syncthreads();

  int r = 0;
  for (int j = 0; j < NG; j++){
    float x = vm[j];
    r += (x < mean) || (x == mean && j < g);
  }
  vs[r] = mean;
  __syncthreads();

  float c0 = (r == 0)    ? vs[0]                     : vs[r-1];
  float c1 = vs[r];
  float c2 = (r == NG-1) ? __fmul_rn(vs[NG-1], 2.0f) : vs[r+1];
  float f0 = __fdiv_rn(__fadd_rn(c0, c1), 1.999f);
  float f1 = __fdiv_rn(__fadd_rn(c1, c2), 2.001f);

  bool ns = (mnf == mxf);
  params[(b*4 + 0)*NG + g] = ns ? 0.0f : mnf;
  params[(b*4 + 1)*NG + g] = ns ? 1.0f : __fsub_rn(mxf, mnf);
  params[(b*4 + 2)*NG + g] = ns ? 1.0f : __fsub_rn(f1, f0);
  params[(b*4 + 3)*NG + g] = ns ? 0.0f : f0;
}

// ---- Pass 5: per-element apply, fp32 replicating reference op order ----
static __device__ __forceinline__ float apply_one(float p, unsigned g,
                                                  const float* __restrict__ sp0,
                                                  const float* __restrict__ sp1,
                                                  const float* __restrict__ sp2,
                                                  const float* __restrict__ sp3){
  float t1  = __fsub_rn(p, sp0[g]);
  float t3  = __fdiv_rn(t1, sp1[g]);
  float t5  = __fmul_rn(t3, sp2[g]);
  float tmp = __fadd_rn(t5, sp3[g]);
  bool bad = __builtin_isnan(tmp) || (tmp == 0.0f);
  float s = __fdiv_rn(p, bad ? 1.0f : tmp);
  bool bad2 = bad || __builtin_isnan(s) || __builtin_isinf(s);
  float sc = bad2 ? 0.0f : s;
  return __fmul_rn(p, sc);
}

__global__ __launch_bounds__(256) void k_apply(const float* __restrict__ pr,
                                               const unsigned* __restrict__ gid32,
                                               const float* __restrict__ params,
                                               float* __restrict__ out){
  __shared__ float sp0[NG], sp1[NG], sp2[NG], sp3[NG];
  const int t = threadIdx.x;
  const int b = blockIdx.x / CD;
  const int c = blockIdx.x % CD;

  sp0[t] = params[(b*4 + 0)*NG + t];
  sp1[t] = params[(b*4 + 1)*NG + t];
  sp2[t] = params[(b*4 + 2)*NG + t];
  sp3[t] = params[(b*4 + 3)*NG + t];
  __syncthreads();

  const size_t base = (size_t)b*NN + (size_t)c*ELD;
  const float4* p4 = (const float4*)(pr + base);
  float4* o4 = (float4*)(out + base);

#pragma unroll
  for (int i = 0; i < ELD/1024; i++){
    float4 p = p4[i*256 + t];
    unsigned pk = gid32[(base >> 2) + i*256 + t];
    float4 r;
    r.x = apply_one(p.x,  pk        & 255u, sp0, sp1, sp2, sp3);
    r.y = apply_one(p.y, (pk >>  8) & 255u, sp0, sp1, sp2, sp3);
    r.z = apply_one(p.z, (pk >> 16) & 255u, sp0, sp1, sp2, sp3);
    r.w = apply_one(p.w,  pk >> 24,         sp0, sp1, sp2, sp3);
    o4[i*256 + t] = r;
  }
}

extern "C" void kernel_launch(void* const* d_in, const int* in_sizes, int n_in,
                              void* d_out, int out_size, void* d_ws, size_t ws_size,
                              hipStream_t stream){
  const float* pr        = (const float*)d_in[0];
  const float* inp_means = (const float*)d_in[1];
  const int*   vr        = (const int*)d_in[2];
  const float* W         = (const float*)d_in[3];
  float* out = (float*)d_out;

  char* ws = (char*)d_ws;
  size_t o = 0;
  unsigned long long* wcnt16 = (unsigned long long*)(ws + o); o += (size_t)NB*NC*NG*8; // 8 MB
  unsigned short* cnt16 = (unsigned short*)(ws + o); o += (size_t)NB*NC*NG*2;          // 2 MB
  unsigned* gid32   = (unsigned*)(ws + o); o += (size_t)NB*NN;       // 8 MB packed u8 gids
  unsigned* grpbase = (unsigned*)(ws + o); o += (size_t)NB*NG*4;     // 32 KB
  unsigned* grplen  = (unsigned*)(ws + o); o += (size_t)NB*NG*4;
  float*    gsum    = (float*)   (ws + o); o += (size_t)NB*NG*4;
  float*    gmn     = (float*)   (ws + o); o += (size_t)NB*NG*4;
  float*    gmx     = (float*)   (ws + o); o += (size_t)NB*NG*4;
  float*    params  = (float*)   (ws + o); o += (size_t)NB*NG*16;    // 128 KB (SoA)
  // sorted values live in d_out (fully overwritten by k_apply afterwards)
  float* sorted = out;

  k_count   <<<NB*NC, 256, 0, stream>>>(vr, wcnt16, cnt16, gid32);
  k_scatter <<<NB*NC, 256, 0, stream>>>(pr, gid32, wcnt16, cnt16, sorted, grpbase, grplen);
  k_sum     <<<NB*8,   32, 0, stream>>>(sorted, grpbase, grplen, gsum, gmn, gmx);
  k_pipeline<<<NB,    256, 0, stream>>>(gsum, gmn, gmx, inp_means, W, params);
  k_apply   <<<NB*CD, 256, 0, stream>>>(pr, gid32, params, out);
}

// Round 11
// 160.170 us; speedup vs baseline: 1.1340x; 1.1340x over previous
//
#include <hip/hip_runtime.h>
#include <math.h>

#define NB 32
#define NN 262144
#define NG 256
#define NC 64             // chunks per batch
#define CH (NN/NC)        // 4096 elements per chunk
#define NW 8              // scatter waves per block (512 threads)
#define SW (CH/NW)        // 512 elements per sub-wave
#define CD 64             // chunks per batch, apply pass
#define ELD (NN/CD)       // 4096 elements per apply block

// ---- Pass 1: per-(batch,chunk,SUBWAVE,group) counts (u16x8 in ulonglong2) +
//      compact u16 chunk totals + packed u8 gid emission. 256 threads; wave w
//      owns elements [w*1024,(w+1)*1024) = sub-waves 2w (i=0,1) and 2w+1
//      (i=2,3), matching k_scatter's 8x512 wave decomposition. ----
__global__ __launch_bounds__(256) void k_count(const int* __restrict__ vr,
                                               ulonglong2* __restrict__ wcnt16,
                                               unsigned short* __restrict__ cnt16,
                                               unsigned* __restrict__ gid32){
  __shared__ unsigned sc[NW][NG];       // 8 KB
  const int t    = threadIdx.x;
  const int lane = t & 63;
  const int w    = t >> 6;
#pragma unroll
  for (int k = 0; k < NW; k++) sc[k][t] = 0u;
  __syncthreads();

  const int b = blockIdx.x / NC;
  const int c = blockIdx.x % NC;
  const size_t base = (size_t)b*NN + (size_t)c*CH;
  const int4* v4 = (const int4*)(vr + base);

#pragma unroll
  for (int i = 0; i < 4; i++){
    int idx = w*256 + i*64 + lane;        // wave-contiguous quarter, coalesced
    int sw  = 2*w + (i >> 1);             // sub-wave (uniform per iteration)
    int4 v = v4[idx];
    atomicAdd(&sc[sw][v.x], 1u);
    atomicAdd(&sc[sw][v.y], 1u);
    atomicAdd(&sc[sw][v.z], 1u);
    atomicAdd(&sc[sw][v.w], 1u);
    gid32[(base >> 2) + idx] =
      (unsigned)v.x | ((unsigned)v.y << 8) | ((unsigned)v.z << 16) | ((unsigned)v.w << 24);
  }
  __syncthreads();

  unsigned s0 = sc[0][t], s1 = sc[1][t], s2 = sc[2][t], s3 = sc[3][t];
  unsigned s4 = sc[4][t], s5 = sc[5][t], s6 = sc[6][t], s7 = sc[7][t];
  const size_t cb = (size_t)b*NC + c;
  ulonglong2 r;
  r.x = (unsigned long long)s0 | ((unsigned long long)s1 << 16)
      | ((unsigned long long)s2 << 32) | ((unsigned long long)s3 << 48);
  r.y = (unsigned long long)s4 | ((unsigned long long)s5 << 16)
      | ((unsigned long long)s6 << 32) | ((unsigned long long)s7 << 48);
  wcnt16[cb*NG + t] = r;
  cnt16 [cb*NG + t] = (unsigned short)(s0+s1+s2+s3+s4+s5+s6+s7);
}

// ---- Pass 2: LDS-staged stable sort + coalesced flush. 512 threads/8 waves:
// 29.8 KB LDS -> 4 blocks/CU x 8 waves = 32 waves (100% occupancy), grid =
// exactly 2 resident rounds. Memory pattern byte-identical to R9 (CH=4096).
// Offsets self-computed from the compact u16 column (2 B/chunk). Placement =
// ds_add_rtn on seeded per-sub-wave counters (R9-proven lane-ordered).
// Order: chunk-major -> sub-wave-major -> stripe -> lane, all preserved ->
// fp32 chain bit-exact.
__global__ __launch_bounds__(512) void k_scatter(const float* __restrict__ pr,
                                                 const unsigned* __restrict__ gid32,
                                                 const ulonglong2* __restrict__ wcnt16,
                                                 const unsigned short* __restrict__ cnt16,
                                                 float* __restrict__ sorted,
                                                 unsigned* __restrict__ grpbase,
                                                 unsigned* __restrict__ grplen){
  __shared__ float vbuf[CH];            // 16 KB sorted values
  __shared__ unsigned char gbuf[CH];    // 4 KB gid per sorted slot
  __shared__ unsigned wcnt[NW][NG];     // 8 KB running counters (seeded)
  __shared__ unsigned bias[NG];         // 1 KB global_dest - local_base
  __shared__ unsigned wsumA[4];
  __shared__ unsigned wsumO[4];
  const int t    = threadIdx.x;         // 0..511
  const int lane = t & 63;
  const int w    = t >> 6;              // 0..7
  const int b = blockIdx.x / NC;
  const int c = blockIdx.x % NC;
  const size_t base = (size_t)b*NN + (size_t)c*CH;

  // phase 0 (threads 0..255; thread t == group id): column walk + fused scans
  unsigned s0=0,s1=0,s2=0,s3=0,s4=0,s5=0,s6=0,s7=0;
  unsigned tot_all=0, tot_before=0, tot_own=0, va=0, vo=0;
  if (t < NG){
    const unsigned short* colT = cnt16 + (size_t)b*NC*NG + t;
#pragma unroll 8
    for (int cc = 0; cc < NC; cc++){
      unsigned tt = colT[(size_t)cc*NG];
      tot_all += tt;
      if (cc < c) tot_before += tt;     // uniform branch per block
    }
    ulonglong2 own = wcnt16[((size_t)b*NC + c)*NG + t];
    unsigned long long lo = own.x, hi = own.y;
    s0 = (unsigned)(lo & 0xFFFF); s1 = (unsigned)((lo >> 16) & 0xFFFF);
    s2 = (unsigned)((lo >> 32) & 0xFFFF); s3 = (unsigned)(lo >> 48);
    s4 = (unsigned)(hi & 0xFFFF); s5 = (unsigned)((hi >> 16) & 0xFFFF);
    s6 = (unsigned)((hi >> 32) & 0xFFFF); s7 = (unsigned)(hi >> 48);
    tot_own = s0+s1+s2+s3+s4+s5+s6+s7;

    va = tot_all; vo = tot_own;         // wave-inclusive scans over lanes
#pragma unroll
    for (int d = 1; d < 64; d <<= 1){
      unsigned ya = __shfl_up(va, d, 64);
      unsigned yo = __shfl_up(vo, d, 64);
      if (lane >= d){ va += ya; vo += yo; }
    }
    if (lane == 63){ wsumA[w] = va; wsumO[w] = vo; }  // w in 0..3 here
  }
  __syncthreads();
  if (t < NG){
    unsigned preA = 0, preO = 0;
#pragma unroll
    for (int k = 0; k < 3; k++) if (k < w){ preA += wsumA[k]; preO += wsumO[k]; }
    unsigned base_g = preA + va - tot_all;      // group base (global)
    unsigned lb     = preO + vo - tot_own;      // local exclusive prefix
    unsigned r = lb;
    wcnt[0][t] = r; r += s0;
    wcnt[1][t] = r; r += s1;
    wcnt[2][t] = r; r += s2;
    wcnt[3][t] = r; r += s3;
    wcnt[4][t] = r; r += s4;
    wcnt[5][t] = r; r += s5;
    wcnt[6][t] = r; r += s6;
    wcnt[7][t] = r;
    bias[t] = (base_g + tot_before) - lb;
    if (c == 0){                                // publish for k_sum
      grpbase[b*NG + t] = base_g;
      grplen [b*NG + t] = tot_all;
    }
  }
  __syncthreads();

  // phase 1: stable scatter into LDS via ds_add_rtn (per sub-wave, element
  // order; 8 stripes, pipelined independent atomics)
  {
    const float*    psrc = pr    + base        + (size_t)w*SW;
    const unsigned* gsrc = gid32 + (base >> 2) + (size_t)w*(SW/4);
    const int shft = (lane & 3) * 8;

    float pv[8]; unsigned pk[8];                // batch all loads upfront
#pragma unroll
    for (int s = 0; s < 8; s++){
      pv[s] = psrc[s*64 + lane];
      pk[s] = gsrc[s*16 + (lane >> 2)];         // 4 lanes share one word
    }
#pragma unroll
    for (int s = 0; s < 8; s++){
      int g = (int)((pk[s] >> shft) & 255u);
      unsigned slot = atomicAdd(&wcnt[w][g], 1u);   // ds_add_rtn_u32
      vbuf[slot] = pv[s];
      gbuf[slot] = (unsigned char)g;
    }
  }
  __syncthreads();

  // phase 2: coalesced flush (consecutive p -> consecutive dest within runs)
  {
    float* dst = sorted + (size_t)b*NN;
    const unsigned* gbuf32 = (const unsigned*)gbuf;
#pragma unroll
    for (int k = 0; k < CH/512; k++){      // 8 iters
      int p = k*512 + t;
      unsigned packed = gbuf32[p >> 2];    // broadcast within 4 threads
      unsigned g = (packed >> ((p & 3) * 8)) & 255u;
      dst[bias[g] + (unsigned)p] = vbuf[p];
    }
  }
}

// ---- Pass 3: one LANE per (batch,group); float4 loads, 8-deep register
//      pipeline. Scalar head to 16B alignment + scalar tail keep the fp32 add
//      chain in exact element order (bit-exact). ----
__global__ __launch_bounds__(32) void k_sum(const float* __restrict__ sorted,
                                            const unsigned* __restrict__ grpbase,
                                            const unsigned* __restrict__ grplen,
                                            float* __restrict__ gsum,
                                            float* __restrict__ gmn,
                                            float* __restrict__ gmx){
  const int lane = threadIdx.x;                  // 0..31
  const int b = blockIdx.x >> 3;                 // 8 blocks per batch
  const int g = ((blockIdx.x & 7) << 5) + lane;  // one group per lane

  const unsigned base = grpbase[b*NG + g];
  const unsigned len  = grplen [b*NG + g];
  const float* sp = sorted + (size_t)b*NN + base;

  float s = 0.0f, mn = INFINITY, mx = -INFINITY;

  unsigned head = (4u - ((unsigned)(((size_t)sp) >> 2) & 3u)) & 3u;
  if (head > len) head = len;
  for (unsigned i = 0; i < head; i++){
    float v = sp[i];
    s = __fadd_rn(s, v); mn = fminf(mn, v); mx = fmaxf(mx, v);
  }
  const float4* f4 = (const float4*)(sp + head);
  const unsigned rem   = len - head;
  const unsigned nfull = rem >> 4;               // 16-elem batches (4 x float4)

  float4 b0[4], b1[4], b2[4], b3[4], b4[4], b5[4], b6[4], b7[4];
#define LOADV(D, K) { D[0]=f4[(K)*4+0]; D[1]=f4[(K)*4+1]; D[2]=f4[(K)*4+2]; D[3]=f4[(K)*4+3]; }
#define CONS1(V)    { s=__fadd_rn(s,(V)); mn=fminf(mn,(V)); mx=fmaxf(mx,(V)); }
#define CONSV(D)    { _Pragma("unroll") for (int j = 0; j < 4; j++){ float4 q = D[j]; \
                      CONS1(q.x) CONS1(q.y) CONS1(q.z) CONS1(q.w) } }

  if (nfull > 0) LOADV(b0, 0)
  if (nfull > 1) LOADV(b1, 1)
  if (nfull > 2) LOADV(b2, 2)
  if (nfull > 3) LOADV(b3, 3)
  if (nfull > 4) LOADV(b4, 4)
  if (nfull > 5) LOADV(b5, 5)
  if (nfull > 6) LOADV(b6, 6)
  if (nfull > 7) LOADV(b7, 7)
  unsigned k = 0;
  for (; k + 8 <= nfull; k += 8){
    CONSV(b0) if (k +  8 < nfull) LOADV(b0, k +  8)
    CONSV(b1) if (k +  9 < nfull) LOADV(b1, k +  9)
    CONSV(b2) if (k + 10 < nfull) LOADV(b2, k + 10)
    CONSV(b3) if (k + 11 < nfull) LOADV(b3, k + 11)
    CONSV(b4) if (k + 12 < nfull) LOADV(b4, k + 12)
    CONSV(b5) if (k + 13 < nfull) LOADV(b5, k + 13)
    CONSV(b6) if (k + 14 < nfull) LOADV(b6, k + 14)
    CONSV(b7) if (k + 15 < nfull) LOADV(b7, k + 15)
  }
  {
    unsigned r = nfull - k;        // 0..7 remaining full batches in b0..b6
    if (r > 0) CONSV(b0)
    if (r > 1) CONSV(b1)
    if (r > 2) CONSV(b2)
    if (r > 3) CONSV(b3)
    if (r > 4) CONSV(b4)
    if (r > 5) CONSV(b5)
    if (r > 6) CONSV(b6)
  }
  for (unsigned i = head + (nfull << 4); i < len; i++){
    float v = sp[i];
    s = __fadd_rn(s, v); mn = fminf(mn, v); mx = fmaxf(mx, v);
  }
#undef LOADV
#undef CONS1
#undef CONSV

  gsum[b*NG + g] = s;
  gmn [b*NG + g] = mn;
  gmx [b*NG + g] = mx;
}

// ---- Pass 4: per-batch group pipeline (blend, stable rank, f0/f1, no_scale) ----
__global__ __launch_bounds__(256) void k_pipeline(const float* __restrict__ gsum,
                                                  const float* __restrict__ gmn,
                                                  const float* __restrict__ gmx,
                                                  const float* __restrict__ inp_means,
                                                  const float* __restrict__ Wv,
                                                  float* __restrict__ params){
  const int b = blockIdx.x;
  const int g = threadIdx.x;
  __shared__ float vm[NG];
  __shared__ float vs[NG];

  const float s   = gsum[b*NG + g];
  const float mnf = gmn [b*NG + g];
  const float mxf = gmx [b*NG + g];
  const float W0 = Wv[0], W1 = Wv[1];
  float mean = __fdiv_rn(__fadd_rn(__fmul_rn(inp_means[b*NG + g], W0),
                                   __fmul_rn(s, W1)),
                         __fadd_rn(W0, W1));
  vm[g] = mean;
  __syncthreads();

  int r = 0;
  for (int j = 0; j < NG; j++){
    float x = vm[j];
    r += (x < mean) || (x == mean && j < g);
  }
  vs[r] = mean;
  __syncthreads();

  float c0 = (r == 0)    ? vs[0]                     : vs[r-1];
  float c1 = vs[r];
  float c2 = (r == NG-1) ? __fmul_rn(vs[NG-1], 2.0f) : vs[r+1];
  float f0 = __fdiv_rn(__fadd_rn(c0, c1), 1.999f);
  float f1 = __fdiv_rn(__fadd_rn(c1, c2), 2.001f);

  bool ns = (mnf == mxf);
  params[(b*4 + 0)*NG + g] = ns ? 0.0f : mnf;
  params[(b*4 + 1)*NG + g] = ns ? 1.0f : __fsub_rn(mxf, mnf);
  params[(b*4 + 2)*NG + g] = ns ? 1.0f : __fsub_rn(f1, f0);
  params[(b*4 + 3)*NG + g] = ns ? 0.0f : f0;
}

// ---- Pass 5: per-element apply, fp32 replicating reference op order ----
static __device__ __forceinline__ float apply_one(float p, unsigned g,
                                                  const float* __restrict__ sp0,
                                                  const float* __restrict__ sp1,
                                                  const float* __restrict__ sp2,
                                                  const float* __restrict__ sp3){
  float t1  = __fsub_rn(p, sp0[g]);
  float t3  = __fdiv_rn(t1, sp1[g]);
  float t5  = __fmul_rn(t3, sp2[g]);
  float tmp = __fadd_rn(t5, sp3[g]);
  bool bad = __builtin_isnan(tmp) || (tmp == 0.0f);
  float s = __fdiv_rn(p, bad ? 1.0f : tmp);
  bool bad2 = bad || __builtin_isnan(s) || __builtin_isinf(s);
  float sc = bad2 ? 0.0f : s;
  return __fmul_rn(p, sc);
}

__global__ __launch_bounds__(256) void k_apply(const float* __restrict__ pr,
                                               const unsigned* __restrict__ gid32,
                                               const float* __restrict__ params,
                                               float* __restrict__ out){
  __shared__ float sp0[NG], sp1[NG], sp2[NG], sp3[NG];
  const int t = threadIdx.x;
  const int b = blockIdx.x / CD;
  const int c = blockIdx.x % CD;

  sp0[t] = params[(b*4 + 0)*NG + t];
  sp1[t] = params[(b*4 + 1)*NG + t];
  sp2[t] = params[(b*4 + 2)*NG + t];
  sp3[t] = params[(b*4 + 3)*NG + t];
  __syncthreads();

  const size_t base = (size_t)b*NN + (size_t)c*ELD;
  const float4* p4 = (const float4*)(pr + base);
  float4* o4 = (float4*)(out + base);

#pragma unroll
  for (int i = 0; i < ELD/1024; i++){
    float4 p = p4[i*256 + t];
    unsigned pk = gid32[(base >> 2) + i*256 + t];
    float4 r;
    r.x = apply_one(p.x,  pk        & 255u, sp0, sp1, sp2, sp3);
    r.y = apply_one(p.y, (pk >>  8) & 255u, sp0, sp1, sp2, sp3);
    r.z = apply_one(p.z, (pk >> 16) & 255u, sp0, sp1, sp2, sp3);
    r.w = apply_one(p.w,  pk >> 24,         sp0, sp1, sp2, sp3);
    o4[i*256 + t] = r;
  }
}

extern "C" void kernel_launch(void* const* d_in, const int* in_sizes, int n_in,
                              void* d_out, int out_size, void* d_ws, size_t ws_size,
                              hipStream_t stream){
  const float* pr        = (const float*)d_in[0];
  const float* inp_means = (const float*)d_in[1];
  const int*   vr        = (const int*)d_in[2];
  const float* W         = (const float*)d_in[3];
  float* out = (float*)d_out;

  char* ws = (char*)d_ws;
  size_t o = 0;
  ulonglong2* wcnt16 = (ulonglong2*)(ws + o); o += (size_t)NB*NC*NG*16;      // 8 MB
  unsigned short* cnt16 = (unsigned short*)(ws + o); o += (size_t)NB*NC*NG*2; // 1 MB
  unsigned* gid32   = (unsigned*)(ws + o); o += (size_t)NB*NN;       // 8 MB packed u8 gids
  unsigned* grpbase = (unsigned*)(ws + o); o += (size_t)NB*NG*4;     // 32 KB
  unsigned* grplen  = (unsigned*)(ws + o); o += (size_t)NB*NG*4;
  float*    gsum    = (float*)   (ws + o); o += (size_t)NB*NG*4;
  float*    gmn     = (float*)   (ws + o); o += (size_t)NB*NG*4;
  float*    gmx     = (float*)   (ws + o); o += (size_t)NB*NG*4;
  float*    params  = (float*)   (ws + o); o += (size_t)NB*NG*16;    // 128 KB (SoA)
  // sorted values live in d_out (fully overwritten by k_apply afterwards)
  float* sorted = out;

  k_count   <<<NB*NC, 256, 0, stream>>>(vr, wcnt16, cnt16, gid32);
  k_scatter <<<NB*NC, 512, 0, stream>>>(pr, gid32, wcnt16, cnt16, sorted, grpbase, grplen);
  k_sum     <<<NB*8,   32, 0, stream>>>(sorted, grpbase, grplen, gsum, gmn, gmx);
  k_pipeline<<<NB,    256, 0, stream>>>(gsum, gmn, gmx, inp_means, W, params);
  k_apply   <<<NB*CD, 256, 0, stream>>>(pr, gid32, params, out);
}